// Round 7
// baseline (1207.007 us; speedup 1.0000x reference)
//
#include <hip/hip_runtime.h>

#define ALPHA 0.005f
#define SCALE 0.001f
#define DELTA 0.1f
#define MAXIT 51   // MAX_ITER + 1 scan steps

constexpr int N = 512;
constexpr int M = 512;
constexpr int NTHREADS = 1024;
constexpr int NWAVES = NTHREADS / 64;  // 16
constexpr int MPW = M / NWAVES;        // 32 constraint rows per wave at t=0
constexpr int NROWS = 256;             // B*S
constexpr size_t WS_NEEDED = (size_t)NROWS * M * N * 2;  // bf16 A copy workspace

// Row map (row m = w + 16*kk; group G = kk>>1, half h = kk&1):
//   kk 0..24  (G0..11 + G12/h0) -> ws stream (12.5 groups = 400 KiB/iter/CU)
//   kk 25     (G12/h1, rows 400..415) -> Ah half-cache (16 KiB)
//   kk 26..31 (G13..15, rows 416..511) -> A_lds cache (96 KiB)
constexpr int CACHE_M0 = 416;

template<int CTRL>
__device__ __forceinline__ float dpp_mov(float v) {
    return __int_as_float(__builtin_amdgcn_update_dpp(
        0, __float_as_int(v), CTRL, 0xF, 0xF, true));
}

// 64-lane sum (t=0 fp32 phase): 6 DPP + readlane
__device__ __forceinline__ float wave_sum_u(float d) {
    d += dpp_mov<0x111>(d);   // row_shr:1
    d += dpp_mov<0x112>(d);   // row_shr:2
    d += dpp_mov<0x114>(d);   // row_shr:4
    d += dpp_mov<0x118>(d);   // row_shr:8
    d += dpp_mov<0x142>(d);   // row_bcast:15
    d += dpp_mov<0x143>(d);   // row_bcast:31
    return __int_as_float(__builtin_amdgcn_readlane(__float_as_int(d), 63));
}

__device__ __forceinline__ float dot8(const float4& a, const float4& c,
                                      const float4& xa, const float4& xb) {
    return a.x*xa.x + a.y*xa.y + a.z*xa.z + a.w*xa.w
         + c.x*xb.x + c.y*xb.y + c.z*xb.z + c.w*xb.w;
}

// bf16 pack (RNE) / unpack
__device__ __forceinline__ unsigned pack2_bf16(float f0, float f1) {
    unsigned a = __float_as_uint(f0); a += 0x7fffu + ((a >> 16) & 1u);
    unsigned b = __float_as_uint(f1); b += 0x7fffu + ((b >> 16) & 1u);
    return (a >> 16) | (b & 0xffff0000u);
}
__device__ __forceinline__ float bflo(unsigned u) { return __uint_as_float(u << 16); }
__device__ __forceinline__ float bfhi(unsigned u) { return __uint_as_float(u & 0xffff0000u); }

__device__ __forceinline__ void unpack4(uint2 u, float4& f) {
    f.x = bflo(u.x); f.y = bfhi(u.x); f.z = bflo(u.y); f.w = bfhi(u.y);
}

// ---------------------------------------------------------------------------
// r2-proven structure + (a) 16 KiB half-group cache (rows 400..415, i.e.
// G12's h==1 half — condition is exactly h==1, wave-half-uniform) and
// (b) 2 barriers/iter (reduced g in separate gred buffer; validated r3/r4).
// Stream = 12.5 groups; caches: 96 KiB A_lds + 16 KiB Ah. VGPR footprint
// identical to r2 (hipcc pins this shape at 64 VGPR — r1/r3/r4 lesson; no
// new persistent per-thread state). Cooperative launch is incompatible with
// graph capture (r6 lesson) — removed.
// ---------------------------------------------------------------------------
__global__ __launch_bounds__(NTHREADS, 4)
void lva_bf16_kernel(const float* __restrict__ x_in,
                     const float* __restrict__ A,
                     const float* __restrict__ bvec,
                     float* __restrict__ x_out,
                     unsigned short* __restrict__ wsA)
{
    __shared__ __align__(16) float b_lds[M];
    __shared__ __align__(16) float g_lds[NWAVES * N];   // 32 KiB: 16 partials
    __shared__ __align__(16) float gred[N];             // 2 KiB: reduced g
    __shared__ __align__(16) float xswap[N];            // 2 KiB: x relayout
    __shared__ float sv_lds[NWAVES];
    __shared__ int bc_active;
    __shared__ __align__(16) uint2 A_lds[96 * 128];     // 96 KiB: rows 416..511
    __shared__ __align__(16) uint2 Ah[16 * 128];        // 16 KiB: rows 400..415

    const int tid  = threadIdx.x;
    const int lane = tid & 63;
    const int w    = tid >> 6;
    const int r    = blockIdx.x;
    const int h    = lane >> 5;          // half-wave index 0/1
    const int s    = lane & 31;          // lane-in-half
    const int xadr = (lane ^ 32) << 2;   // bpermute byte addr (xor32)

    if (tid < M) b_lds[tid] = bvec[(size_t)r * M + tid];

    const int n0 = lane * 4;
    const int n1 = 256 + lane * 4;

    const float* xrow = x_in + (size_t)r * N;
    float4 xa = *(const float4*)(xrow + n0);
    float4 xb = *(const float4*)(xrow + n1);

    const float* Ablk = A + (size_t)r * M * N + (size_t)w * N;
    unsigned short* Wblk = wsA + (size_t)r * M * N + (size_t)w * N;

    __syncthreads();

    bool alive = true;

    // ---- t = 0: fp32 compute; A -> ws (kk 0..24) / Ah (kk 25) / A_lds ----
    {
        float4 ga = make_float4(0.f, 0.f, 0.f, 0.f);
        float4 gb = make_float4(0.f, 0.f, 0.f, 0.f);
        float sviol = 0.f;
        float4 a0, a1, a2, a3, c0, c1, c2, c3;

        #define LOADA4(KK) do {                                               \
            const float* P0 = Ablk + (size_t)((KK) + 0) * (16 * N);           \
            const float* P1 = Ablk + (size_t)((KK) + 1) * (16 * N);           \
            const float* P2 = Ablk + (size_t)((KK) + 2) * (16 * N);           \
            const float* P3 = Ablk + (size_t)((KK) + 3) * (16 * N);           \
            a0 = *(const float4*)(P0 + n0); c0 = *(const float4*)(P0 + n1);   \
            a1 = *(const float4*)(P1 + n0); c1 = *(const float4*)(P1 + n1);   \
            a2 = *(const float4*)(P2 + n0); c2 = *(const float4*)(P2 + n1);   \
            a3 = *(const float4*)(P3 + n0); c3 = *(const float4*)(P3 + n1);   \
        } while (0)

        #define DOTGRAD4(KK) do {                                             \
            float bb0 = b_lds[w + 16 * ((KK) + 0)];                           \
            float bb1 = b_lds[w + 16 * ((KK) + 1)];                           \
            float bb2 = b_lds[w + 16 * ((KK) + 2)];                           \
            float bb3 = b_lds[w + 16 * ((KK) + 3)];                           \
            float d0 = wave_sum_u(dot8(a0, c0, xa, xb));                      \
            float d1 = wave_sum_u(dot8(a1, c1, xa, xb));                      \
            float d2 = wave_sum_u(dot8(a2, c2, xa, xb));                      \
            float d3 = wave_sum_u(dot8(a3, c3, xa, xb));                      \
            float v0 = fmaxf(d0 - bb0, 0.f);                                  \
            float v1 = fmaxf(d1 - bb1, 0.f);                                  \
            float v2 = fmaxf(d2 - bb2, 0.f);                                  \
            float v3 = fmaxf(d3 - bb3, 0.f);                                  \
            sviol += v0 + v1 + v2 + v3;                                       \
            ga.x += v0*a0.x + v1*a1.x + v2*a2.x + v3*a3.x;                    \
            ga.y += v0*a0.y + v1*a1.y + v2*a2.y + v3*a3.y;                    \
            ga.z += v0*a0.z + v1*a1.z + v2*a2.z + v3*a3.z;                    \
            ga.w += v0*a0.w + v1*a1.w + v2*a2.w + v3*a3.w;                    \
            gb.x += v0*c0.x + v1*c1.x + v2*c2.x + v3*c3.x;                    \
            gb.y += v0*c0.y + v1*c1.y + v2*c2.y + v3*c3.y;                    \
            gb.z += v0*c0.z + v1*c1.z + v2*c2.z + v3*c3.z;                    \
            gb.w += v0*c0.w + v1*c1.w + v2*c2.w + v3*c3.w;                    \
        } while (0)

        #define WS1(J, AJ, CJ) do {                                           \
            unsigned short* qq = Wblk + (size_t)(J) * (16 * N);               \
            *(uint2*)(qq + n0) = make_uint2(pack2_bf16(AJ.x, AJ.y),           \
                                            pack2_bf16(AJ.z, AJ.w));          \
            *(uint2*)(qq + n1) = make_uint2(pack2_bf16(CJ.x, CJ.y),           \
                                            pack2_bf16(CJ.z, CJ.w));          \
        } while (0)

        #define LDS1(J, AJ, CJ) do {                                          \
            const int rl = w + 16 * (J) - CACHE_M0;                           \
            A_lds[rl * 128 + lane]      = make_uint2(pack2_bf16(AJ.x, AJ.y),  \
                                                     pack2_bf16(AJ.z, AJ.w)); \
            A_lds[rl * 128 + 64 + lane] = make_uint2(pack2_bf16(CJ.x, CJ.y),  \
                                                     pack2_bf16(CJ.z, CJ.w)); \
        } while (0)

        // kk 0..23 -> ws groups 0..11 (rolled)
        #pragma unroll 1
        for (int kk = 0; kk < 24; kk += 4) {
            LOADA4(kk);
            WS1(kk + 0, a0, c0); WS1(kk + 1, a1, c1);
            WS1(kk + 2, a2, c2); WS1(kk + 3, a3, c3);
            DOTGRAD4(kk);
        }
        // kk 24 -> ws (G12/h0); kk 25 -> Ah (G12/h1); kk 26,27 -> A_lds
        LOADA4(24);
        WS1(24, a0, c0);
        Ah[w * 128 + lane]      = make_uint2(pack2_bf16(a1.x, a1.y),
                                             pack2_bf16(a1.z, a1.w));
        Ah[w * 128 + 64 + lane] = make_uint2(pack2_bf16(c1.x, c1.y),
                                             pack2_bf16(c1.z, c1.w));
        LDS1(26, a2, c2); LDS1(27, a3, c3);
        DOTGRAD4(24);
        // kk 28..31 -> A_lds (G14, G15)
        LOADA4(28);
        LDS1(28, a0, c0); LDS1(29, a1, c1);
        LDS1(30, a2, c2); LDS1(31, a3, c3);
        DOTGRAD4(28);

        #undef LOADA4
        #undef WS1
        #undef LDS1
        #undef DOTGRAD4

        if (lane == 0) sv_lds[w] = sviol;
        *(float4*)(&g_lds[w * N + n0]) = ga;
        *(float4*)(&g_lds[w * N + n1]) = gb;
        __syncthreads();
        if (tid == 0) {
            float s_ = 0.f;
            #pragma unroll
            for (int i = 0; i < NWAVES; ++i) s_ += sv_lds[i];
            bc_active = (s_ >= DELTA) ? 1 : 0;
        }
        if (tid < N) {
            float s_ = 0.f;
            #pragma unroll
            for (int i = 0; i < NWAVES; ++i) s_ += g_lds[i * N + tid];
            gred[tid] = s_;
        }
        __syncthreads();
        if (!bc_active) {
            alive = false;
        } else {
            float4 gfa = *(const float4*)(&gred[n0]);
            float4 gfb = *(const float4*)(&gred[n1]);
            xa.x = fmaxf(xa.x - (ALPHA / (1.f + SCALE*gfa.x)) * gfa.x, 0.f);
            xa.y = fmaxf(xa.y - (ALPHA / (1.f + SCALE*gfa.y)) * gfa.y, 0.f);
            xa.z = fmaxf(xa.z - (ALPHA / (1.f + SCALE*gfa.z)) * gfa.z, 0.f);
            xa.w = fmaxf(xa.w - (ALPHA / (1.f + SCALE*gfa.w)) * gfa.w, 0.f);
            xb.x = fmaxf(xb.x - (ALPHA / (1.f + SCALE*gfb.x)) * gfb.x, 0.f);
            xb.y = fmaxf(xb.y - (ALPHA / (1.f + SCALE*gfb.y)) * gfb.y, 0.f);
            xb.z = fmaxf(xb.z - (ALPHA / (1.f + SCALE*gfb.z)) * gfb.z, 0.f);
            xb.w = fmaxf(xb.w - (ALPHA / (1.f + SCALE*gfb.w)) * gfb.w, 0.f);
        }
    }

    // ---- relayout x into 32-lane-group fragments (s*4 contiguous) ----
    if (w == 0) {
        *(float4*)(&xswap[n0]) = xa;
        *(float4*)(&xswap[n1]) = xb;
    }
    __syncthreads();
    float4 xf0 = *(const float4*)(&xswap[  0 + s * 4]);
    float4 xf1 = *(const float4*)(&xswap[128 + s * 4]);
    float4 xf2 = *(const float4*)(&xswap[256 + s * 4]);
    float4 xf3 = *(const float4*)(&xswap[384 + s * 4]);

    // ---- t = 1..50: bf16 phase, half-wave per row, double-buffered ----
    if (alive) {
        const uint2* Wp = (const uint2*)(wsA + (size_t)r * M * N)
                          + (w + 16 * h) * 128 + s;
        const int mb = w + 16 * h;    // b_lds base; row m = mb + 32*G

        uint2 c0, c1, c2, c3, p0, p1, p2, p3;

        #define LOADG(b0, b1, b2, b3, Gn) do {  \
            b0 = Wp[(Gn) * 4096];               \
            b1 = Wp[(Gn) * 4096 + 32];          \
            b2 = Wp[(Gn) * 4096 + 64];          \
            b3 = Wp[(Gn) * 4096 + 96];          \
        } while (0)

        #define COMPUTE(b0, b1, b2, b3, G) do {                               \
            float4 f0, f1, f2, f3;                                            \
            unpack4(b0, f0); unpack4(b1, f1);                                 \
            unpack4(b2, f2); unpack4(b3, f3);                                 \
            float d = f0.x*xf0.x + f0.y*xf0.y + f0.z*xf0.z + f0.w*xf0.w       \
                    + f1.x*xf1.x + f1.y*xf1.y + f1.z*xf1.z + f1.w*xf1.w       \
                    + f2.x*xf2.x + f2.y*xf2.y + f2.z*xf2.z + f2.w*xf2.w       \
                    + f3.x*xf3.x + f3.y*xf3.y + f3.z*xf3.z + f3.w*xf3.w;      \
            d += dpp_mov<0xB1>(d);   /* quad_perm [1,0,3,2] : xor1 */         \
            d += dpp_mov<0x4E>(d);   /* quad_perm [2,3,0,1] : xor2 */         \
            d += dpp_mov<0x141>(d);  /* row_half_mirror     : xor4 */         \
            d += dpp_mov<0x140>(d);  /* row_mirror          : xor8 */         \
            d += __int_as_float(__builtin_amdgcn_ds_swizzle(                  \
                     __float_as_int(d), 0x401F)); /* xor16 within 32 */       \
            float v = fmaxf(d - b_lds[mb + 32 * (G)], 0.f);                   \
            sviol += v;                                                       \
            g0.x += v*f0.x; g0.y += v*f0.y; g0.z += v*f0.z; g0.w += v*f0.w;   \
            g1.x += v*f1.x; g1.y += v*f1.y; g1.z += v*f1.z; g1.w += v*f1.w;   \
            g2.x += v*f2.x; g2.y += v*f2.y; g2.z += v*f2.z; g2.w += v*f2.w;   \
            g3.x += v*f3.x; g3.y += v*f3.y; g3.z += v*f3.z; g3.w += v*f3.w;   \
        } while (0)

        #define MRG(x) (x) += __int_as_float(                                 \
            __builtin_amdgcn_ds_bpermute(xadr, __float_as_int(x)))

        LOADG(c0, c1, c2, c3, 0);   // prologue: G=0 in flight

        #pragma unroll 1
        for (int t = 1; t < MAXIT; ++t) {
            float4 g0 = make_float4(0.f, 0.f, 0.f, 0.f);
            float4 g1 = make_float4(0.f, 0.f, 0.f, 0.f);
            float4 g2 = make_float4(0.f, 0.f, 0.f, 0.f);
            float4 g3 = make_float4(0.f, 0.f, 0.f, 0.f);
            float sviol = 0.f;

            // 12 full ws groups, paired double-buffer
            #pragma unroll 1
            for (int G = 0; G < 10; G += 2) {
                LOADG(p0, p1, p2, p3, G + 1);
                COMPUTE(c0, c1, c2, c3, G);
                LOADG(c0, c1, c2, c3, G + 2);
                COMPUTE(p0, p1, p2, p3, G + 1);
            }
            LOADG(p0, p1, p2, p3, 11);
            COMPUTE(c0, c1, c2, c3, 10);
            if (h == 0) LOADG(c0, c1, c2, c3, 12);   // G12: h0 half from ws
            COMPUTE(p0, p1, p2, p3, 11);
            if (h == 1) {                            // G12: h1 half from Ah
                const int base = w * 128 + s;
                c0 = Ah[base];      c1 = Ah[base + 32];
                c2 = Ah[base + 64]; c3 = Ah[base + 96];
            }
            COMPUTE(c0, c1, c2, c3, 12);
            LOADG(c0, c1, c2, c3, 0);
            // ^ next-iter G0 in flight across 3 LDS groups + reduce + barriers

            // 3 LDS-cached groups (rows 416..511), reuse p-ring registers
            {
                const int base = mb * 128 + s;
                p0 = A_lds[base]; p1 = A_lds[base + 32];
                p2 = A_lds[base + 64]; p3 = A_lds[base + 96];
                COMPUTE(p0, p1, p2, p3, 13);
            }
            {
                const int base = (mb + 32) * 128 + s;
                p0 = A_lds[base]; p1 = A_lds[base + 32];
                p2 = A_lds[base + 64]; p3 = A_lds[base + 96];
                COMPUTE(p0, p1, p2, p3, 14);
            }
            {
                const int base = (mb + 64) * 128 + s;
                p0 = A_lds[base]; p1 = A_lds[base + 32];
                p2 = A_lds[base + 64]; p3 = A_lds[base + 96];
                COMPUTE(p0, p1, p2, p3, 15);
            }

            // merge half-wave partials in-register (xor32) -> 16 partials
            MRG(g0.x); MRG(g0.y); MRG(g0.z); MRG(g0.w);
            MRG(g1.x); MRG(g1.y); MRG(g1.z); MRG(g1.w);
            MRG(g2.x); MRG(g2.y); MRG(g2.z); MRG(g2.w);
            MRG(g3.x); MRG(g3.y); MRG(g3.z); MRG(g3.w);
            MRG(sviol);

            if (h == 0) {
                const int gb_ = w * N + s * 4;
                *(float4*)(&g_lds[gb_      ]) = g0;
                *(float4*)(&g_lds[gb_ + 128]) = g1;
                *(float4*)(&g_lds[gb_ + 256]) = g2;
                *(float4*)(&g_lds[gb_ + 384]) = g3;
                if (s == 0) sv_lds[w] = sviol;
            }
            __syncthreads();                       // barrier 1
            if (tid == 0) {
                float sacc = 0.f;
                #pragma unroll
                for (int i = 0; i < NWAVES; ++i) sacc += sv_lds[i];
                bc_active = (sacc >= DELTA) ? 1 : 0;
            }
            if (tid < N) {
                float sacc = 0.f;
                #pragma unroll
                for (int i = 0; i < NWAVES; ++i) sacc += g_lds[i * N + tid];
                gred[tid] = sacc;
            }
            __syncthreads();                       // barrier 2
            if (!bc_active) break;

            float4 q0 = *(const float4*)(&gred[  0 + s * 4]);
            float4 q1 = *(const float4*)(&gred[128 + s * 4]);
            float4 q2 = *(const float4*)(&gred[256 + s * 4]);
            float4 q3 = *(const float4*)(&gred[384 + s * 4]);
            xf0.x = fmaxf(xf0.x - (ALPHA / (1.f + SCALE*q0.x)) * q0.x, 0.f);
            xf0.y = fmaxf(xf0.y - (ALPHA / (1.f + SCALE*q0.y)) * q0.y, 0.f);
            xf0.z = fmaxf(xf0.z - (ALPHA / (1.f + SCALE*q0.z)) * q0.z, 0.f);
            xf0.w = fmaxf(xf0.w - (ALPHA / (1.f + SCALE*q0.w)) * q0.w, 0.f);
            xf1.x = fmaxf(xf1.x - (ALPHA / (1.f + SCALE*q1.x)) * q1.x, 0.f);
            xf1.y = fmaxf(xf1.y - (ALPHA / (1.f + SCALE*q1.y)) * q1.y, 0.f);
            xf1.z = fmaxf(xf1.z - (ALPHA / (1.f + SCALE*q1.z)) * q1.z, 0.f);
            xf1.w = fmaxf(xf1.w - (ALPHA / (1.f + SCALE*q1.w)) * q1.w, 0.f);
            xf2.x = fmaxf(xf2.x - (ALPHA / (1.f + SCALE*q2.x)) * q2.x, 0.f);
            xf2.y = fmaxf(xf2.y - (ALPHA / (1.f + SCALE*q2.y)) * q2.y, 0.f);
            xf2.z = fmaxf(xf2.z - (ALPHA / (1.f + SCALE*q2.z)) * q2.z, 0.f);
            xf2.w = fmaxf(xf2.w - (ALPHA / (1.f + SCALE*q2.w)) * q2.w, 0.f);
            xf3.x = fmaxf(xf3.x - (ALPHA / (1.f + SCALE*q3.x)) * q3.x, 0.f);
            xf3.y = fmaxf(xf3.y - (ALPHA / (1.f + SCALE*q3.y)) * q3.y, 0.f);
            xf3.z = fmaxf(xf3.z - (ALPHA / (1.f + SCALE*q3.z)) * q3.z, 0.f);
            xf3.w = fmaxf(xf3.w - (ALPHA / (1.f + SCALE*q3.w)) * q3.w, 0.f);
            // no 3rd barrier: gred (read here) is disjoint from g_lds
            // (written next iter pre-barrier-1); barriers 1/2 order them.
        }
        #undef LOADG
        #undef COMPUTE
        #undef MRG
    }

    if (w == 0 && h == 0) {   // x replicated across waves/halves
        float* orow = x_out + (size_t)r * N + s * 4;
        *(float4*)(orow +   0) = xf0;
        *(float4*)(orow + 128) = xf1;
        *(float4*)(orow + 256) = xf2;
        *(float4*)(orow + 384) = xf3;
    }
}

// ---------------------------------------------------------------------------
// Fallback (proven fp32 kernel) if ws_size < 128 MiB.
// ---------------------------------------------------------------------------
__global__ __launch_bounds__(NTHREADS, 4)
void lva_kernel(const float* __restrict__ x_in,
                const float* __restrict__ A,
                const float* __restrict__ bvec,
                float* __restrict__ x_out)
{
    __shared__ float b_lds[M];
    __shared__ float g_lds[NWAVES * N];
    __shared__ float sv_lds[NWAVES];
    __shared__ int bc_active;

    const int tid  = threadIdx.x;
    const int lane = tid & 63;
    const int w    = tid >> 6;
    const int r    = blockIdx.x;

    if (tid < M) b_lds[tid] = bvec[(size_t)r * M + tid];

    const int n0 = lane * 4;
    const int n1 = 256 + lane * 4;

    const float* xrow = x_in + (size_t)r * N;
    float4 xa = *(const float4*)(xrow + n0);
    float4 xb = *(const float4*)(xrow + n1);

    const float* Ablk = A + (size_t)r * M * N + (size_t)w * N;

    __syncthreads();

    for (int t = 0; t < MAXIT; ++t) {
        float4 ga = make_float4(0.f, 0.f, 0.f, 0.f);
        float4 gb = make_float4(0.f, 0.f, 0.f, 0.f);
        float sviol = 0.f;

        #pragma unroll 1
        for (int kk = 0; kk < MPW; kk += 4) {
            const float* p0 = Ablk + (size_t)(kk + 0) * (16 * N);
            const float* p1 = Ablk + (size_t)(kk + 1) * (16 * N);
            const float* p2 = Ablk + (size_t)(kk + 2) * (16 * N);
            const float* p3 = Ablk + (size_t)(kk + 3) * (16 * N);
            float4 a0 = *(const float4*)(p0 + n0), c0 = *(const float4*)(p0 + n1);
            float4 a1 = *(const float4*)(p1 + n0), c1 = *(const float4*)(p1 + n1);
            float4 a2 = *(const float4*)(p2 + n0), c2 = *(const float4*)(p2 + n1);
            float4 a3 = *(const float4*)(p3 + n0), c3 = *(const float4*)(p3 + n1);
            float bb0 = b_lds[w + 16 * (kk + 0)];
            float bb1 = b_lds[w + 16 * (kk + 1)];
            float bb2 = b_lds[w + 16 * (kk + 2)];
            float bb3 = b_lds[w + 16 * (kk + 3)];
            float d0 = wave_sum_u(dot8(a0, c0, xa, xb));
            float d1 = wave_sum_u(dot8(a1, c1, xa, xb));
            float d2 = wave_sum_u(dot8(a2, c2, xa, xb));
            float d3 = wave_sum_u(dot8(a3, c3, xa, xb));
            float v0 = fmaxf(d0 - bb0, 0.f);
            float v1 = fmaxf(d1 - bb1, 0.f);
            float v2 = fmaxf(d2 - bb2, 0.f);
            float v3 = fmaxf(d3 - bb3, 0.f);
            sviol += v0 + v1 + v2 + v3;
            ga.x += v0*a0.x + v1*a1.x + v2*a2.x + v3*a3.x;
            ga.y += v0*a0.y + v1*a1.y + v2*a2.y + v3*a3.y;
            ga.z += v0*a0.z + v1*a1.z + v2*a2.z + v3*a3.z;
            ga.w += v0*a0.w + v1*a1.w + v2*a2.w + v3*a3.w;
            gb.x += v0*c0.x + v1*c1.x + v2*c2.x + v3*c3.x;
            gb.y += v0*c0.y + v1*c1.y + v2*c2.y + v3*c3.y;
            gb.z += v0*c0.z + v1*c1.z + v2*c2.z + v3*c3.z;
            gb.w += v0*c0.w + v1*c1.w + v2*c2.w + v3*c3.w;
        }

        if (lane == 0) sv_lds[w] = sviol;
        *(float4*)(&g_lds[w * N + n0]) = ga;
        *(float4*)(&g_lds[w * N + n1]) = gb;
        __syncthreads();
        if (tid == 0) {
            float sacc = 0.f;
            #pragma unroll
            for (int i = 0; i < NWAVES; ++i) sacc += sv_lds[i];
            bc_active = (sacc >= DELTA) ? 1 : 0;
        }
        if (tid < N) {
            float sacc = 0.f;
            #pragma unroll
            for (int i = 0; i < NWAVES; ++i) sacc += g_lds[i * N + tid];
            g_lds[tid] = sacc;
        }
        __syncthreads();
        if (!bc_active) break;

        float4 gfa = *(const float4*)(&g_lds[n0]);
        float4 gfb = *(const float4*)(&g_lds[n1]);
        xa.x = fmaxf(xa.x - (ALPHA / (1.f + SCALE*gfa.x)) * gfa.x, 0.f);
        xa.y = fmaxf(xa.y - (ALPHA / (1.f + SCALE*gfa.y)) * gfa.y, 0.f);
        xa.z = fmaxf(xa.z - (ALPHA / (1.f + SCALE*gfa.z)) * gfa.z, 0.f);
        xa.w = fmaxf(xa.w - (ALPHA / (1.f + SCALE*gfa.w)) * gfa.w, 0.f);
        xb.x = fmaxf(xb.x - (ALPHA / (1.f + SCALE*gfb.x)) * gfb.x, 0.f);
        xb.y = fmaxf(xb.y - (ALPHA / (1.f + SCALE*gfb.y)) * gfb.y, 0.f);
        xb.z = fmaxf(xb.z - (ALPHA / (1.f + SCALE*gfb.z)) * gfb.z, 0.f);
        xb.w = fmaxf(xb.w - (ALPHA / (1.f + SCALE*gfb.w)) * gfb.w, 0.f);
        __syncthreads();
    }

    float* orow = x_out + (size_t)r * N;
    if (w == 0) {
        *(float4*)(orow + n0) = xa;
        *(float4*)(orow + n1) = xb;
    }
}

extern "C" void kernel_launch(void* const* d_in, const int* in_sizes, int n_in,
                              void* d_out, int out_size, void* d_ws, size_t ws_size,
                              hipStream_t stream)
{
    const float* x  = (const float*)d_in[0];
    const float* A  = (const float*)d_in[1];
    const float* b  = (const float*)d_in[2];
    float* out      = (float*)d_out;

    if (ws_size >= WS_NEEDED) {
        lva_bf16_kernel<<<dim3(NROWS), dim3(NTHREADS), 0, stream>>>(
            x, A, b, out, (unsigned short*)d_ws);
    } else {
        lva_kernel<<<dim3(NROWS), dim3(NTHREADS), 0, stream>>>(x, A, b, out);
    }
}

// Round 8
// 1145.862 us; speedup vs baseline: 1.0534x; 1.0534x over previous
//
#include <hip/hip_runtime.h>

#define ALPHA 0.005f
#define SCALE 0.001f
#define DELTA 0.1f
#define MAXIT 51   // MAX_ITER + 1 scan steps

constexpr int N = 512;
constexpr int M = 512;
constexpr int NTHREADS = 1024;
constexpr int NWAVES = NTHREADS / 64;  // 16
constexpr int MPW = M / NWAVES;        // 32 constraint rows per wave at t=0
constexpr int NROWS = 256;             // B*S
constexpr size_t WS_NEEDED = (size_t)NROWS * M * N * 2;  // bf16 A copy: 128 MiB

// rows m in [416,512) (groups 13,14,15) live in LDS, never touch the ws copy
constexpr int CACHE_M0 = 416;
constexpr int CACHE_KK0 = 26;          // m = w + 16*kk >= 416  <=>  kk >= 26

template<int CTRL>
__device__ __forceinline__ float dpp_mov(float v) {
    return __int_as_float(__builtin_amdgcn_update_dpp(
        0, __float_as_int(v), CTRL, 0xF, 0xF, true));
}

// 64-lane sum (t=0 fp32 phase): 6 DPP + readlane
__device__ __forceinline__ float wave_sum_u(float d) {
    d += dpp_mov<0x111>(d);   // row_shr:1
    d += dpp_mov<0x112>(d);   // row_shr:2
    d += dpp_mov<0x114>(d);   // row_shr:4
    d += dpp_mov<0x118>(d);   // row_shr:8
    d += dpp_mov<0x142>(d);   // row_bcast:15
    d += dpp_mov<0x143>(d);   // row_bcast:31
    return __int_as_float(__builtin_amdgcn_readlane(__float_as_int(d), 63));
}

__device__ __forceinline__ float dot8(const float4& a, const float4& c,
                                      const float4& xa, const float4& xb) {
    return a.x*xa.x + a.y*xa.y + a.z*xa.z + a.w*xa.w
         + c.x*xb.x + c.y*xb.y + c.z*xb.z + c.w*xb.w;
}

// bf16 pack (RNE) / unpack
__device__ __forceinline__ unsigned pack2_bf16(float f0, float f1) {
    unsigned a = __float_as_uint(f0); a += 0x7fffu + ((a >> 16) & 1u);
    unsigned b = __float_as_uint(f1); b += 0x7fffu + ((b >> 16) & 1u);
    return (a >> 16) | (b & 0xffff0000u);
}
__device__ __forceinline__ float bflo(unsigned u) { return __uint_as_float(u << 16); }
__device__ __forceinline__ float bfhi(unsigned u) { return __uint_as_float(u & 0xffff0000u); }

__device__ __forceinline__ void unpack4(uint2 u, float4& f) {
    f.x = bflo(u.x); f.y = bfhi(u.x); f.z = bflo(u.y); f.w = bfhi(u.y);
}

// ---------------------------------------------------------------------------
// One block per (b,s) row (per-row inactivity is absorbing — validated r1-r4).
// t=0: fp32 pass (64-lane layout) computes update #1; stores bf16 A to ws for
//      rows < 416, rows 416..511 go to a 96 KiB LDS cache instead.
// t>=1: proven structure — half-wave per row, 16 elems/lane (uint2),
//      2-deep double-buffered loads, 13 global groups + 3 LDS groups.
//      Half-wave partials merged in-register via ds_bpermute xor32 so g_lds
//      shrinks to 32 KiB (16 partials), making room for the A cache.
// This is the session-best configuration (910 µs). Attempts that regressed,
// with cause: reg-cache (r1/r3/r4: hipcc pins 1024-thread kernels at 64 VGPR
// -> scratch spill), LDS ds_add reduction (r5: same-address contention),
// 2-block/row cooperative split (r6: cooperative launch illegal under graph
// capture + (1024,8) bound -> 32 VGPR spill), half-group cache + barrier
// removal (r7: load-issue-distance loss, +66 µs).
// ---------------------------------------------------------------------------
__global__ __launch_bounds__(NTHREADS, 4)
void lva_bf16_kernel(const float* __restrict__ x_in,
                     const float* __restrict__ A,
                     const float* __restrict__ bvec,
                     float* __restrict__ x_out,
                     unsigned short* __restrict__ wsA)
{
    __shared__ __align__(16) float b_lds[M];
    __shared__ __align__(16) float g_lds[NWAVES * N];      // 32 KiB: 16 partials
    __shared__ float sv_lds[NWAVES];
    __shared__ int bc_active;
    __shared__ __align__(16) uint2 A_lds[96 * 128];        // 96 KiB: rows 416..511

    const int tid  = threadIdx.x;
    const int lane = tid & 63;
    const int w    = tid >> 6;
    const int r    = blockIdx.x;

    if (tid < M) b_lds[tid] = bvec[(size_t)r * M + tid];

    const int n0 = lane * 4;
    const int n1 = 256 + lane * 4;

    const float* xrow = x_in + (size_t)r * N;
    float4 xa = *(const float4*)(xrow + n0);
    float4 xb = *(const float4*)(xrow + n1);

    const float* Ablk = A + (size_t)r * M * N + (size_t)w * N;
    unsigned short* Wblk = wsA + (size_t)r * M * N + (size_t)w * N;

    __syncthreads();

    bool alive = true;

    // ---- t = 0: fp32 compute + bf16 convert (ws for m<416, LDS else) ----
    {
        float4 ga = make_float4(0.f, 0.f, 0.f, 0.f);
        float4 gb = make_float4(0.f, 0.f, 0.f, 0.f);
        float sviol = 0.f;

        #define STROW(j, aj, cj) do {                                               \
            if (kk + (j) >= CACHE_KK0) {                                            \
                const int rl = w + 16 * (kk + (j)) - CACHE_M0;                      \
                A_lds[rl * 128 + lane]      = make_uint2(pack2_bf16(aj.x, aj.y),    \
                                                         pack2_bf16(aj.z, aj.w));   \
                A_lds[rl * 128 + 64 + lane] = make_uint2(pack2_bf16(cj.x, cj.y),    \
                                                         pack2_bf16(cj.z, cj.w));   \
            } else {                                                                \
                unsigned short* q = Wblk + (size_t)(kk + (j)) * (16 * N);           \
                *(uint2*)(q + n0) = make_uint2(pack2_bf16(aj.x, aj.y),              \
                                               pack2_bf16(aj.z, aj.w));             \
                *(uint2*)(q + n1) = make_uint2(pack2_bf16(cj.x, cj.y),              \
                                               pack2_bf16(cj.z, cj.w));             \
            }                                                                       \
        } while (0)

        #pragma unroll 1
        for (int kk = 0; kk < MPW; kk += 4) {
            const float* p0 = Ablk + (size_t)(kk + 0) * (16 * N);
            const float* p1 = Ablk + (size_t)(kk + 1) * (16 * N);
            const float* p2 = Ablk + (size_t)(kk + 2) * (16 * N);
            const float* p3 = Ablk + (size_t)(kk + 3) * (16 * N);
            float4 a0 = *(const float4*)(p0 + n0), c0 = *(const float4*)(p0 + n1);
            float4 a1 = *(const float4*)(p1 + n0), c1 = *(const float4*)(p1 + n1);
            float4 a2 = *(const float4*)(p2 + n0), c2 = *(const float4*)(p2 + n1);
            float4 a3 = *(const float4*)(p3 + n0), c3 = *(const float4*)(p3 + n1);
            STROW(0, a0, c0); STROW(1, a1, c1); STROW(2, a2, c2); STROW(3, a3, c3);
            float bb0 = b_lds[w + 16 * (kk + 0)];
            float bb1 = b_lds[w + 16 * (kk + 1)];
            float bb2 = b_lds[w + 16 * (kk + 2)];
            float bb3 = b_lds[w + 16 * (kk + 3)];
            float d0 = wave_sum_u(dot8(a0, c0, xa, xb));
            float d1 = wave_sum_u(dot8(a1, c1, xa, xb));
            float d2 = wave_sum_u(dot8(a2, c2, xa, xb));
            float d3 = wave_sum_u(dot8(a3, c3, xa, xb));
            float v0 = fmaxf(d0 - bb0, 0.f);
            float v1 = fmaxf(d1 - bb1, 0.f);
            float v2 = fmaxf(d2 - bb2, 0.f);
            float v3 = fmaxf(d3 - bb3, 0.f);
            sviol += v0 + v1 + v2 + v3;
            ga.x += v0*a0.x + v1*a1.x + v2*a2.x + v3*a3.x;
            ga.y += v0*a0.y + v1*a1.y + v2*a2.y + v3*a3.y;
            ga.z += v0*a0.z + v1*a1.z + v2*a2.z + v3*a3.z;
            ga.w += v0*a0.w + v1*a1.w + v2*a2.w + v3*a3.w;
            gb.x += v0*c0.x + v1*c1.x + v2*c2.x + v3*c3.x;
            gb.y += v0*c0.y + v1*c1.y + v2*c2.y + v3*c3.y;
            gb.z += v0*c0.z + v1*c1.z + v2*c2.z + v3*c3.z;
            gb.w += v0*c0.w + v1*c1.w + v2*c2.w + v3*c3.w;
        }
        #undef STROW

        if (lane == 0) sv_lds[w] = sviol;
        *(float4*)(&g_lds[w * N + n0]) = ga;
        *(float4*)(&g_lds[w * N + n1]) = gb;
        __syncthreads();
        if (tid == 0) {
            float s = 0.f;
            #pragma unroll
            for (int i = 0; i < NWAVES; ++i) s += sv_lds[i];
            bc_active = (s >= DELTA) ? 1 : 0;
        }
        if (tid < N) {
            float s = 0.f;
            #pragma unroll
            for (int i = 0; i < NWAVES; ++i) s += g_lds[i * N + tid];
            g_lds[tid] = s;
        }
        __syncthreads();
        if (!bc_active) {
            alive = false;
        } else {
            float4 gfa = *(const float4*)(&g_lds[n0]);
            float4 gfb = *(const float4*)(&g_lds[n1]);
            xa.x = fmaxf(xa.x - (ALPHA / (1.f + SCALE*gfa.x)) * gfa.x, 0.f);
            xa.y = fmaxf(xa.y - (ALPHA / (1.f + SCALE*gfa.y)) * gfa.y, 0.f);
            xa.z = fmaxf(xa.z - (ALPHA / (1.f + SCALE*gfa.z)) * gfa.z, 0.f);
            xa.w = fmaxf(xa.w - (ALPHA / (1.f + SCALE*gfa.w)) * gfa.w, 0.f);
            xb.x = fmaxf(xb.x - (ALPHA / (1.f + SCALE*gfb.x)) * gfb.x, 0.f);
            xb.y = fmaxf(xb.y - (ALPHA / (1.f + SCALE*gfb.y)) * gfb.y, 0.f);
            xb.z = fmaxf(xb.z - (ALPHA / (1.f + SCALE*gfb.z)) * gfb.z, 0.f);
            xb.w = fmaxf(xb.w - (ALPHA / (1.f + SCALE*gfb.w)) * gfb.w, 0.f);
        }
    }

    // ---- relayout x into 32-lane-group fragments (s*4 contiguous) ----
    const int h = lane >> 5;          // half-wave index 0/1
    const int s = lane & 31;          // lane-in-half
    __syncthreads();
    if (w == 0) {
        *(float4*)(&g_lds[n0]) = xa;
        *(float4*)(&g_lds[n1]) = xb;
    }
    __syncthreads();
    float4 xf0 = *(const float4*)(&g_lds[  0 + s * 4]);
    float4 xf1 = *(const float4*)(&g_lds[128 + s * 4]);
    float4 xf2 = *(const float4*)(&g_lds[256 + s * 4]);
    float4 xf3 = *(const float4*)(&g_lds[384 + s * 4]);
    __syncthreads();

    // ---- t = 1..50: bf16 phase, half-wave per row, double-buffered ----
    if (alive) {
        // lane's uint2 pointer: block + row (w+16h) + s-th uint2
        const uint2* Wp = (const uint2*)(wsA + (size_t)r * M * N)
                          + (w + 16 * h) * 128 + s;
        const int mb = w + 16 * h;    // b_lds base; row m = mb + 32*G
        const int xadr = (lane ^ 32) << 2;   // bpermute byte addr (xor32)

        uint2 c0, c1, c2, c3, p0, p1, p2, p3;

        #define LOADG(b0, b1, b2, b3, Gn) do {  \
            b0 = Wp[(Gn) * 4096];               \
            b1 = Wp[(Gn) * 4096 + 32];          \
            b2 = Wp[(Gn) * 4096 + 64];          \
            b3 = Wp[(Gn) * 4096 + 96];          \
        } while (0)

        #define COMPUTE(b0, b1, b2, b3, G) do {                               \
            float4 f0, f1, f2, f3;                                            \
            unpack4(b0, f0); unpack4(b1, f1);                                 \
            unpack4(b2, f2); unpack4(b3, f3);                                 \
            float d = f0.x*xf0.x + f0.y*xf0.y + f0.z*xf0.z + f0.w*xf0.w       \
                    + f1.x*xf1.x + f1.y*xf1.y + f1.z*xf1.z + f1.w*xf1.w       \
                    + f2.x*xf2.x + f2.y*xf2.y + f2.z*xf2.z + f2.w*xf2.w       \
                    + f3.x*xf3.x + f3.y*xf3.y + f3.z*xf3.z + f3.w*xf3.w;      \
            d += dpp_mov<0xB1>(d);   /* quad_perm [1,0,3,2] : xor1 */         \
            d += dpp_mov<0x4E>(d);   /* quad_perm [2,3,0,1] : xor2 */         \
            d += dpp_mov<0x141>(d);  /* row_half_mirror     : xor4 */         \
            d += dpp_mov<0x140>(d);  /* row_mirror          : xor8 */         \
            d += __int_as_float(__builtin_amdgcn_ds_swizzle(                  \
                     __float_as_int(d), 0x401F)); /* xor16 within 32 */       \
            float v = fmaxf(d - b_lds[mb + 32 * (G)], 0.f);                   \
            sviol += v;                                                       \
            g0.x += v*f0.x; g0.y += v*f0.y; g0.z += v*f0.z; g0.w += v*f0.w;   \
            g1.x += v*f1.x; g1.y += v*f1.y; g1.z += v*f1.z; g1.w += v*f1.w;   \
            g2.x += v*f2.x; g2.y += v*f2.y; g2.z += v*f2.z; g2.w += v*f2.w;   \
            g3.x += v*f3.x; g3.y += v*f3.y; g3.z += v*f3.z; g3.w += v*f3.w;   \
        } while (0)

        #define MRG(x) (x) += __int_as_float(                                 \
            __builtin_amdgcn_ds_bpermute(xadr, __float_as_int(x)))

        LOADG(c0, c1, c2, c3, 0);   // prologue: G=0 in flight

        #pragma unroll 1
        for (int t = 1; t < MAXIT; ++t) {
            float4 g0 = make_float4(0.f, 0.f, 0.f, 0.f);
            float4 g1 = make_float4(0.f, 0.f, 0.f, 0.f);
            float4 g2 = make_float4(0.f, 0.f, 0.f, 0.f);
            float4 g3 = make_float4(0.f, 0.f, 0.f, 0.f);
            float sviol = 0.f;

            // 12 global groups, paired double-buffer (proven)
            #pragma unroll 1
            for (int G = 0; G < 12; G += 2) {
                LOADG(p0, p1, p2, p3, G + 1);
                COMPUTE(c0, c1, c2, c3, G);
                LOADG(c0, c1, c2, c3, G + 2);
                COMPUTE(p0, p1, p2, p3, G + 1);
            }
            // G=12 (last global group), then issue next-iter G0 load —
            // in flight across 3 LDS groups + reduction + barriers
            COMPUTE(c0, c1, c2, c3, 12);
            LOADG(c0, c1, c2, c3, 0);

            // 3 LDS-cached groups (rows 416..511), reuse p-ring registers
            {
                const int base = mb * 128 + s;
                p0 = A_lds[base]; p1 = A_lds[base + 32];
                p2 = A_lds[base + 64]; p3 = A_lds[base + 96];
                COMPUTE(p0, p1, p2, p3, 13);
            }
            {
                const int base = (mb + 32) * 128 + s;
                p0 = A_lds[base]; p1 = A_lds[base + 32];
                p2 = A_lds[base + 64]; p3 = A_lds[base + 96];
                COMPUTE(p0, p1, p2, p3, 14);
            }
            {
                const int base = (mb + 64) * 128 + s;
                p0 = A_lds[base]; p1 = A_lds[base + 32];
                p2 = A_lds[base + 64]; p3 = A_lds[base + 96];
                COMPUTE(p0, p1, p2, p3, 15);
            }

            // merge half-wave partials in-register (xor32) -> 16 partials
            MRG(g0.x); MRG(g0.y); MRG(g0.z); MRG(g0.w);
            MRG(g1.x); MRG(g1.y); MRG(g1.z); MRG(g1.w);
            MRG(g2.x); MRG(g2.y); MRG(g2.z); MRG(g2.w);
            MRG(g3.x); MRG(g3.y); MRG(g3.z); MRG(g3.w);
            MRG(sviol);

            if (h == 0) {
                const int gb = w * N + s * 4;
                *(float4*)(&g_lds[gb      ]) = g0;
                *(float4*)(&g_lds[gb + 128]) = g1;
                *(float4*)(&g_lds[gb + 256]) = g2;
                *(float4*)(&g_lds[gb + 384]) = g3;
                if (s == 0) sv_lds[w] = sviol;
            }
            __syncthreads();
            if (tid == 0) {
                float sacc = 0.f;
                #pragma unroll
                for (int i = 0; i < NWAVES; ++i) sacc += sv_lds[i];
                bc_active = (sacc >= DELTA) ? 1 : 0;
            }
            if (tid < N) {
                float sacc = 0.f;
                #pragma unroll
                for (int i = 0; i < NWAVES; ++i) sacc += g_lds[i * N + tid];
                g_lds[tid] = sacc;
            }
            __syncthreads();
            if (!bc_active) break;

            float4 q0 = *(const float4*)(&g_lds[  0 + s * 4]);
            float4 q1 = *(const float4*)(&g_lds[128 + s * 4]);
            float4 q2 = *(const float4*)(&g_lds[256 + s * 4]);
            float4 q3 = *(const float4*)(&g_lds[384 + s * 4]);
            xf0.x = fmaxf(xf0.x - (ALPHA / (1.f + SCALE*q0.x)) * q0.x, 0.f);
            xf0.y = fmaxf(xf0.y - (ALPHA / (1.f + SCALE*q0.y)) * q0.y, 0.f);
            xf0.z = fmaxf(xf0.z - (ALPHA / (1.f + SCALE*q0.z)) * q0.z, 0.f);
            xf0.w = fmaxf(xf0.w - (ALPHA / (1.f + SCALE*q0.w)) * q0.w, 0.f);
            xf1.x = fmaxf(xf1.x - (ALPHA / (1.f + SCALE*q1.x)) * q1.x, 0.f);
            xf1.y = fmaxf(xf1.y - (ALPHA / (1.f + SCALE*q1.y)) * q1.y, 0.f);
            xf1.z = fmaxf(xf1.z - (ALPHA / (1.f + SCALE*q1.z)) * q1.z, 0.f);
            xf1.w = fmaxf(xf1.w - (ALPHA / (1.f + SCALE*q1.w)) * q1.w, 0.f);
            xf2.x = fmaxf(xf2.x - (ALPHA / (1.f + SCALE*q2.x)) * q2.x, 0.f);
            xf2.y = fmaxf(xf2.y - (ALPHA / (1.f + SCALE*q2.y)) * q2.y, 0.f);
            xf2.z = fmaxf(xf2.z - (ALPHA / (1.f + SCALE*q2.z)) * q2.z, 0.f);
            xf2.w = fmaxf(xf2.w - (ALPHA / (1.f + SCALE*q2.w)) * q2.w, 0.f);
            xf3.x = fmaxf(xf3.x - (ALPHA / (1.f + SCALE*q3.x)) * q3.x, 0.f);
            xf3.y = fmaxf(xf3.y - (ALPHA / (1.f + SCALE*q3.y)) * q3.y, 0.f);
            xf3.z = fmaxf(xf3.z - (ALPHA / (1.f + SCALE*q3.z)) * q3.z, 0.f);
            xf3.w = fmaxf(xf3.w - (ALPHA / (1.f + SCALE*q3.w)) * q3.w, 0.f);
            __syncthreads();   // protect g_lds before next iter's writes
        }
        #undef LOADG
        #undef COMPUTE
        #undef MRG
    }

    if (w == 0 && h == 0) {   // x replicated across waves/halves
        float* orow = x_out + (size_t)r * N + s * 4;
        *(float4*)(orow +   0) = xf0;
        *(float4*)(orow + 128) = xf1;
        *(float4*)(orow + 256) = xf2;
        *(float4*)(orow + 384) = xf3;
    }
}

// ---------------------------------------------------------------------------
// Fallback (proven fp32 kernel) if ws_size < 128 MiB.
// ---------------------------------------------------------------------------
__global__ __launch_bounds__(NTHREADS, 4)
void lva_kernel(const float* __restrict__ x_in,
                const float* __restrict__ A,
                const float* __restrict__ bvec,
                float* __restrict__ x_out)
{
    __shared__ float b_lds[M];
    __shared__ float g_lds[NWAVES * N];
    __shared__ float sv_lds[NWAVES];
    __shared__ int bc_active;

    const int tid  = threadIdx.x;
    const int lane = tid & 63;
    const int w    = tid >> 6;
    const int r    = blockIdx.x;

    if (tid < M) b_lds[tid] = bvec[(size_t)r * M + tid];

    const int n0 = lane * 4;
    const int n1 = 256 + lane * 4;

    const float* xrow = x_in + (size_t)r * N;
    float4 xa = *(const float4*)(xrow + n0);
    float4 xb = *(const float4*)(xrow + n1);

    const float* Ablk = A + (size_t)r * M * N + (size_t)w * N;

    __syncthreads();

    for (int t = 0; t < MAXIT; ++t) {
        float4 ga = make_float4(0.f, 0.f, 0.f, 0.f);
        float4 gb = make_float4(0.f, 0.f, 0.f, 0.f);
        float sviol = 0.f;

        #pragma unroll 1
        for (int kk = 0; kk < MPW; kk += 4) {
            const float* p0 = Ablk + (size_t)(kk + 0) * (16 * N);
            const float* p1 = Ablk + (size_t)(kk + 1) * (16 * N);
            const float* p2 = Ablk + (size_t)(kk + 2) * (16 * N);
            const float* p3 = Ablk + (size_t)(kk + 3) * (16 * N);
            float4 a0 = *(const float4*)(p0 + n0), c0 = *(const float4*)(p0 + n1);
            float4 a1 = *(const float4*)(p1 + n0), c1 = *(const float4*)(p1 + n1);
            float4 a2 = *(const float4*)(p2 + n0), c2 = *(const float4*)(p2 + n1);
            float4 a3 = *(const float4*)(p3 + n0), c3 = *(const float4*)(p3 + n1);
            float bb0 = b_lds[w + 16 * (kk + 0)];
            float bb1 = b_lds[w + 16 * (kk + 1)];
            float bb2 = b_lds[w + 16 * (kk + 2)];
            float bb3 = b_lds[w + 16 * (kk + 3)];
            float d0 = wave_sum_u(dot8(a0, c0, xa, xb));
            float d1 = wave_sum_u(dot8(a1, c1, xa, xb));
            float d2 = wave_sum_u(dot8(a2, c2, xa, xb));
            float d3 = wave_sum_u(dot8(a3, c3, xa, xb));
            float v0 = fmaxf(d0 - bb0, 0.f);
            float v1 = fmaxf(d1 - bb1, 0.f);
            float v2 = fmaxf(d2 - bb2, 0.f);
            float v3 = fmaxf(d3 - bb3, 0.f);
            sviol += v0 + v1 + v2 + v3;
            ga.x += v0*a0.x + v1*a1.x + v2*a2.x + v3*a3.x;
            ga.y += v0*a0.y + v1*a1.y + v2*a2.y + v3*a3.y;
            ga.z += v0*a0.z + v1*a1.z + v2*a2.z + v3*a3.z;
            ga.w += v0*a0.w + v1*a1.w + v2*a2.w + v3*a3.w;
            gb.x += v0*c0.x + v1*c1.x + v2*c2.x + v3*c3.x;
            gb.y += v0*c0.y + v1*c1.y + v2*c2.y + v3*c3.y;
            gb.z += v0*c0.z + v1*c1.z + v2*c2.z + v3*c3.z;
            gb.w += v0*c0.w + v1*c1.w + v2*c2.w + v3*c3.w;
        }

        if (lane == 0) sv_lds[w] = sviol;
        *(float4*)(&g_lds[w * N + n0]) = ga;
        *(float4*)(&g_lds[w * N + n1]) = gb;
        __syncthreads();
        if (tid == 0) {
            float sacc = 0.f;
            #pragma unroll
            for (int i = 0; i < NWAVES; ++i) sacc += sv_lds[i];
            bc_active = (sacc >= DELTA) ? 1 : 0;
        }
        if (tid < N) {
            float sacc = 0.f;
            #pragma unroll
            for (int i = 0; i < NWAVES; ++i) sacc += g_lds[i * N + tid];
            g_lds[tid] = sacc;
        }
        __syncthreads();
        if (!bc_active) break;

        float4 gfa = *(const float4*)(&g_lds[n0]);
        float4 gfb = *(const float4*)(&g_lds[n1]);
        xa.x = fmaxf(xa.x - (ALPHA / (1.f + SCALE*gfa.x)) * gfa.x, 0.f);
        xa.y = fmaxf(xa.y - (ALPHA / (1.f + SCALE*gfa.y)) * gfa.y, 0.f);
        xa.z = fmaxf(xa.z - (ALPHA / (1.f + SCALE*gfa.z)) * gfa.z, 0.f);
        xa.w = fmaxf(xa.w - (ALPHA / (1.f + SCALE*gfa.w)) * gfa.w, 0.f);
        xb.x = fmaxf(xb.x - (ALPHA / (1.f + SCALE*gfb.x)) * gfb.x, 0.f);
        xb.y = fmaxf(xb.y - (ALPHA / (1.f + SCALE*gfb.y)) * gfb.y, 0.f);
        xb.z = fmaxf(xb.z - (ALPHA / (1.f + SCALE*gfb.z)) * gfb.z, 0.f);
        xb.w = fmaxf(xb.w - (ALPHA / (1.f + SCALE*gfb.w)) * gfb.w, 0.f);
        __syncthreads();
    }

    float* orow = x_out + (size_t)r * N;
    if (w == 0) {
        *(float4*)(orow + n0) = xa;
        *(float4*)(orow + n1) = xb;
    }
}

extern "C" void kernel_launch(void* const* d_in, const int* in_sizes, int n_in,
                              void* d_out, int out_size, void* d_ws, size_t ws_size,
                              hipStream_t stream)
{
    const float* x  = (const float*)d_in[0];
    const float* A  = (const float*)d_in[1];
    const float* b  = (const float*)d_in[2];
    float* out      = (float*)d_out;

    if (ws_size >= WS_NEEDED) {
        lva_bf16_kernel<<<dim3(NROWS), dim3(NTHREADS), 0, stream>>>(
            x, A, b, out, (unsigned short*)d_ws);
    } else {
        lva_kernel<<<dim3(NROWS), dim3(NTHREADS), 0, stream>>>(x, A, b, out);
    }
}